// Round 1
// baseline (552.924 us; speedup 1.0000x reference)
//
#include <hip/hip_runtime.h>
#include <cmath>

#define NM 32768   // 512 * 64 matrices
#define ND 32      // matrix side

// Broadcast from lane L within each 32-lane group (ds_swizzle BitMode: and=0, or=L, xor=0)
template<int L>
__device__ __forceinline__ float bcast32(float x) {
    return __int_as_float(__builtin_amdgcn_ds_swizzle(__float_as_int(x), (L << 5)));
}

// ---------- Cholesky (right-looking, rank-1 updates). Lane r holds row r in a[0..31].
// Valid entries: a[j] for j <= r. Upper slots hold garbage, never read.
template<int J, int L>
__device__ __forceinline__ void rank1_upd(float (&a)[ND], float lrj) {
    if constexpr (L < ND) {
        float blj = bcast32<L>(lrj);          // L[l][J] from lane l
        a[L] = fmaf(-lrj, blj, a[L]);
        rank1_upd<J, L + 1>(a, lrj);
    }
}

template<int J>
__device__ __forceinline__ void chol_steps(float (&a)[ND], int r) {
    if constexpr (J < ND) {
        float ajj = bcast32<J>(a[J]);         // updated A[J][J] from lane J
        float d = sqrtf(ajj);
        float rinv = 1.0f / d;
        float lrj = (r == J) ? d : a[J] * rinv;  // final L[r][J] (garbage for r<J)
        a[J] = lrj;
        rank1_upd<J, J + 1>(a, lrj);
        chol_steps<J + 1>(a, r);
    }
}

// ---------- L * L^T. Lane r holds row r of L_out in b[] (zeros above diag, diag included).
// Lane r computes o_c = sum_j b_r[j] * b_c[j] = out[r][c] = out[c][r]; stores transposed
// (symmetry) => coalesced stores.
template<int C, int J>
__device__ __forceinline__ float llt_dot(const float (&b)[ND], float acc) {
    if constexpr (J <= C) {
        float bcj = bcast32<C>(b[J]);
        return llt_dot<C, J + 1>(b, fmaf(b[J], bcj, acc));
    } else {
        return acc;
    }
}

template<int C>
__device__ __forceinline__ void llt_store(const float (&b)[ND], float* om, int r) {
    if constexpr (C < ND) {
        float v = llt_dot<C, 0>(b, 0.0f);
        om[C * ND + r] = v;                   // out[C][r] == out[r][C]
        llt_store<C + 1>(b, om, r);
    }
}

// ws layout (floats):
//   [0    .. 1023] : sum of strictly-lower L, TRANSPOSED: slot j*32+r holds sum over m of L[r][j] (j<r)
//   [1024 .. 1055] : sum of log(diag)
//   [1056]         : S2 = sum over m of (||sl||^2 + ||logd||^2)
//   [1088 .. 2111] : fmT  = factor * sl_mean (same transposed layout)
//   [2112 .. 2143] : fmd  = factor * logd_mean
//   [2144]         : factor

__global__ __launch_bounds__(256) void k1_stats(const float* __restrict__ X,
                                                float* __restrict__ gacc) {
    __shared__ float lacc[1057];
    int tid = threadIdx.x;
    for (int i = tid; i < 1057; i += 256) lacc[i] = 0.0f;
    __syncthreads();

    int lane = tid & 63;
    int r = lane & 31;
    int wave = tid >> 6;

    for (int pass = 0; pass < 16; ++pass) {
        int mp = (blockIdx.x * 16 + pass) * 4 + wave;   // matrix-pair id
        int mat = mp * 2 + (lane >> 5);
        const float* xm = X + (size_t)mat * (ND * ND);

        float a[ND];
        #pragma unroll
        for (int j = 0; j < ND; ++j) a[j] = xm[j * ND + r];  // row r via symmetry (coalesced)

        chol_steps<0>(a, r);

        // diag extract without dynamic register indexing
        float diag = a[0];
        #pragma unroll
        for (int j = 1; j < ND; ++j) diag = (r == j) ? a[j] : diag;
        float logd = logf(diag);

        // per-lane squared norm (strict lower + logd^2)
        float sq = logd * logd;
        #pragma unroll
        for (int j = 0; j < ND; ++j) if (j < r) sq = fmaf(a[j], a[j], sq);
        // wave-wide sum (covers both matrices)
        #pragma unroll
        for (int k = 1; k < 64; k <<= 1) sq += __shfl_xor(sq, k);
        if (lane == 0) atomicAdd(&lacc[1056], sq);

        // linear sums: transposed LDS layout -> bank r, conflict-free; halves share addr (2-way, free)
        #pragma unroll
        for (int j = 0; j < ND; ++j) if (j < r) atomicAdd(&lacc[j * ND + r], a[j]);
        atomicAdd(&lacc[1024 + r], logd);
    }

    __syncthreads();
    for (int i = tid; i < 1057; i += 256) atomicAdd(&gacc[i], lacc[i]);
}

__global__ __launch_bounds__(256) void k2_final(const float* __restrict__ sscal,
                                                float* __restrict__ ws) {
    __shared__ float red[256];
    __shared__ float sfactor;
    int tid = threadIdx.x;
    const float invM = 1.0f / (float)NM;

    float msq = 0.0f;
    for (int k = tid; k < 1056; k += 256) {
        float m = ws[k] * invM;
        msq = fmaf(m, m, msq);
    }
    red[tid] = msq;
    __syncthreads();
    for (int s = 128; s > 0; s >>= 1) {
        if (tid < s) red[tid] += red[tid + s];
        __syncthreads();
    }
    if (tid == 0) {
        float var = ws[1056] * invM - red[0];
        float f = sscal[0] / sqrtf(var);
        sfactor = f;
        ws[2144] = f;
    }
    __syncthreads();
    float f = sfactor;
    for (int k = tid; k < 1056; k += 256) {
        ws[1088 + k] = f * (ws[k] * invM);
    }
}

__global__ __launch_bounds__(256) void k3_out(const float* __restrict__ X,
                                              const float* __restrict__ wsf,
                                              float* __restrict__ out) {
    int tid = threadIdx.x;
    int lane = tid & 63;
    int r = lane & 31;
    int wave = tid >> 6;
    int mat = (blockIdx.x * 4 + wave) * 2 + (lane >> 5);

    const float* xm = X + (size_t)mat * (ND * ND);
    float a[ND];
    #pragma unroll
    for (int j = 0; j < ND; ++j) a[j] = xm[j * ND + r];

    chol_steps<0>(a, r);

    float factor = wsf[1056];

    float diag = a[0];
    #pragma unroll
    for (int j = 1; j < ND; ++j) diag = (r == j) ? a[j] : diag;
    float dval = expf(fmaf(factor, logf(diag), -wsf[1024 + r]));

    // L_out row r: strict lower = factor*L - factor*mean; diag = dval; above diag = 0
    #pragma unroll
    for (int j = 0; j < ND; ++j) {
        float b = fmaf(factor, a[j], -wsf[j * ND + r]);   // wsf slots unused for j>=r are 0
        a[j] = (j < r) ? b : ((j == r) ? dval : 0.0f);
    }

    float* om = out + (size_t)mat * (ND * ND);
    llt_store<0>(a, om, r);
}

extern "C" void kernel_launch(void* const* d_in, const int* in_sizes, int n_in,
                              void* d_out, int out_size, void* d_ws, size_t ws_size,
                              hipStream_t stream) {
    const float* X = (const float*)d_in[0];
    const float* s = (const float*)d_in[1];
    float* out = (float*)d_out;
    float* ws = (float*)d_ws;

    hipMemsetAsync(ws, 0, 1057 * sizeof(float), stream);
    hipLaunchKernelGGL(k1_stats, dim3(256), dim3(256), 0, stream, X, ws);
    hipLaunchKernelGGL(k2_final, dim3(1), dim3(256), 0, stream, s, ws);
    hipLaunchKernelGGL(k3_out, dim3(4096), dim3(256), 0, stream, X, ws + 1088, out);
}

// Round 4
// 515.743 us; speedup vs baseline: 1.0721x; 1.0721x over previous
//
#include <hip/hip_runtime.h>
#include <cmath>

#define NM 32768   // 512 * 64 matrices
#define ND 32      // matrix side

typedef __attribute__((ext_vector_type(8))) short short8;     // 8 bf16 (4 VGPRs)
typedef __attribute__((ext_vector_type(16))) float f32x16;    // MFMA accumulator

// Broadcast from lane L within each 32-lane group (ds_swizzle BitMode: and=0, or=L, xor=0)
template<int L>
__device__ __forceinline__ float bcast32(float x) {
    return __int_as_float(__builtin_amdgcn_ds_swizzle(__float_as_int(x), (L << 5)));
}

// ---------- Cholesky (right-looking, rank-1 updates). Lane r holds row r in a[0..31].
template<int J, int L>
__device__ __forceinline__ void rank1_upd(float (&a)[ND], float lrj) {
    if constexpr (L < ND) {
        float blj = bcast32<L>(lrj);          // L[l][J] from lane l
        a[L] = fmaf(-lrj, blj, a[L]);
        rank1_upd<J, L + 1>(a, lrj);
    }
}

template<int J>
__device__ __forceinline__ void chol_steps(float (&a)[ND], int r) {
    if constexpr (J < ND) {
        float ajj = bcast32<J>(a[J]);         // updated A[J][J] from lane J
        float d = sqrtf(ajj);
        float rinv = 1.0f / d;
        float lrj = (r == J) ? d : a[J] * rinv;  // final L[r][J] (garbage for r<J)
        a[J] = lrj;
        rank1_upd<J, J + 1>(a, lrj);
        chol_steps<J + 1>(a, r);
    }
}

union frag_u { short8 v; int i[4]; };

// Build complete MFMA fragments for both half-wave-resident matrices.
// mine_lo/mine_hi: this lane's own-matrix row data packed for the hi=0 / hi=1
// k-slots. Cross-half exchange via __shfl_xor(.,32) (ds_bpermute, guaranteed
// semantics across the full 64-lane wave).
// f0 = fragment of lanes-0..31's matrix, f1 = fragment of lanes-32..63's matrix.
__device__ __forceinline__ void build_frags(const frag_u& mine_lo, const frag_u& mine_hi,
                                            bool hi_half, frag_u& f0, frag_u& f1) {
    #pragma unroll
    for (int w = 0; w < 4; ++w) {
        int olo = __shfl_xor(mine_lo.i[w], 32);   // other half's lo-pack
        int ohi = __shfl_xor(mine_hi.i[w], 32);   // other half's hi-pack
        f0.i[w] = hi_half ? ohi : mine_lo.i[w];
        f1.i[w] = hi_half ? mine_hi.i[w] : olo;
    }
}

// ws layout (floats):
//   [0    .. 1023] : sum of strictly-lower L, TRANSPOSED: slot j*32+r = sum_m L[r][j] (j<r)
//   [1024 .. 1055] : sum of log(diag)
//   [1056]         : S2 = sum over m of (||sl||^2 + ||logd||^2)
//   [1088 .. 2111] : fmT = factor * sl_mean (same transposed layout)
//   [2112 .. 2143] : fmd = factor * logd_mean
//   [2144]         : factor

__global__ __launch_bounds__(256) void k1_stats(const float* __restrict__ X,
                                                float* __restrict__ gacc) {
    __shared__ float lacc[1057];
    int tid = threadIdx.x;
    for (int i = tid; i < 1057; i += 256) lacc[i] = 0.0f;
    __syncthreads();

    int lane = tid & 63;
    int r = lane & 31;
    int wave = tid >> 6;

    for (int pass = 0; pass < 2; ++pass) {
        int mp = (blockIdx.x * 2 + pass) * 4 + wave;   // matrix-pair id
        int mat = mp * 2 + (lane >> 5);
        const float* xm = X + (size_t)mat * (ND * ND);

        float a[ND];
        #pragma unroll
        for (int j = 0; j < ND; ++j) a[j] = xm[j * ND + r];  // row r via symmetry (coalesced)

        chol_steps<0>(a, r);

        float diag = a[0];
        #pragma unroll
        for (int j = 1; j < ND; ++j) diag = (r == j) ? a[j] : diag;
        float logd = logf(diag);

        float sq = logd * logd;
        #pragma unroll
        for (int j = 0; j < ND; ++j) if (j < r) sq = fmaf(a[j], a[j], sq);
        #pragma unroll
        for (int k = 1; k < 64; k <<= 1) sq += __shfl_xor(sq, k);
        if (lane == 0) atomicAdd(&lacc[1056], sq);

        // transposed LDS layout -> bank r, conflict-free; halves share addr (2-way, free)
        #pragma unroll
        for (int j = 0; j < ND; ++j) if (j < r) atomicAdd(&lacc[j * ND + r], a[j]);
        atomicAdd(&lacc[1024 + r], logd);
    }

    __syncthreads();
    for (int i = tid; i < 1057; i += 256) atomicAdd(&gacc[i], lacc[i]);
}

__global__ __launch_bounds__(256) void k2_final(const float* __restrict__ sscal,
                                                float* __restrict__ ws) {
    __shared__ float red[256];
    __shared__ float sfactor;
    int tid = threadIdx.x;
    const float invM = 1.0f / (float)NM;

    float msq = 0.0f;
    for (int k = tid; k < 1056; k += 256) {
        float m = ws[k] * invM;
        msq = fmaf(m, m, msq);
    }
    red[tid] = msq;
    __syncthreads();
    for (int s = 128; s > 0; s >>= 1) {
        if (tid < s) red[tid] += red[tid + s];
        __syncthreads();
    }
    if (tid == 0) {
        float var = ws[1056] * invM - red[0];
        float f = sscal[0] / sqrtf(var);
        sfactor = f;
        ws[2144] = f;
    }
    __syncthreads();
    float f = sfactor;
    for (int k = tid; k < 1056; k += 256) {
        ws[1088 + k] = f * (ws[k] * invM);
    }
}

__global__ __launch_bounds__(256) void k3_out(const float* __restrict__ X,
                                              const float* __restrict__ wsf,
                                              float* __restrict__ out) {
    int tid = threadIdx.x;
    int lane = tid & 63;
    int r = lane & 31;
    int wave = tid >> 6;
    int pair = blockIdx.x * 4 + wave;
    int mat = pair * 2 + (lane >> 5);
    bool hi_half = (lane >> 5) != 0;

    const float* xm = X + (size_t)mat * (ND * ND);
    float a[ND];
    #pragma unroll
    for (int j = 0; j < ND; ++j) a[j] = xm[j * ND + r];

    chol_steps<0>(a, r);

    float factor = wsf[1056];

    float diag = a[0];
    #pragma unroll
    for (int j = 1; j < ND; ++j) diag = (r == j) ? a[j] : diag;
    float dval = expf(fmaf(factor, logf(diag), -wsf[1024 + r]));

    // L_out row r of own matrix: strict lower = factor*(L - mean); diag = dval; upper = 0
    #pragma unroll
    for (int j = 0; j < ND; ++j) {
        float b = fmaf(factor, a[j], -wsf[j * ND + r]);
        a[j] = (j < r) ? b : ((j == r) ? dval : 0.0f);
    }

    // ---- out = L_out * L_out^T via bf16 hi/lo MFMA (error ~1e-3 vs 3e-2 threshold).
    // k-packing is permutation-invariant here: with identical A/B register
    // contents and symmetric A/B layouts, D = sum_k L[r][pi(k)] L[c][pi(k)]
    // for any bijective packing pi. So pack simply: elem i -> k = kb + i (lo),
    // kb + 8 + i (hi).
    f32x16 acc0, acc1;
    #pragma unroll
    for (int g = 0; g < 16; ++g) { acc0[g] = 0.0f; acc1[g] = 0.0f; }

    #pragma unroll
    for (int kb = 0; kb < 32; kb += 16) {
        frag_u mlo_h, mhi_h, mlo_l, mhi_l;
        #pragma unroll
        for (int i = 0; i < 8; ++i) {
            float v0 = a[kb + i], v1 = a[kb + 8 + i];
            __bf16 hb0 = (__bf16)v0, hb1 = (__bf16)v1;
            mlo_h.v[i] = __builtin_bit_cast(short, hb0);
            mhi_h.v[i] = __builtin_bit_cast(short, hb1);
            mlo_l.v[i] = __builtin_bit_cast(short, (__bf16)(v0 - (float)hb0));
            mhi_l.v[i] = __builtin_bit_cast(short, (__bf16)(v1 - (float)hb1));
        }
        frag_u h0, h1, l0, l1;
        build_frags(mlo_h, mhi_h, hi_half, h0, h1);
        build_frags(mlo_l, mhi_l, hi_half, l0, l1);
        acc0 = __builtin_amdgcn_mfma_f32_32x32x16_bf16(h0.v, h0.v, acc0, 0, 0, 0);
        acc1 = __builtin_amdgcn_mfma_f32_32x32x16_bf16(h1.v, h1.v, acc1, 0, 0, 0);
        acc0 = __builtin_amdgcn_mfma_f32_32x32x16_bf16(h0.v, l0.v, acc0, 0, 0, 0);
        acc1 = __builtin_amdgcn_mfma_f32_32x32x16_bf16(h1.v, l1.v, acc1, 0, 0, 0);
        acc0 = __builtin_amdgcn_mfma_f32_32x32x16_bf16(l0.v, h0.v, acc0, 0, 0, 0);
        acc1 = __builtin_amdgcn_mfma_f32_32x32x16_bf16(l1.v, h1.v, acc1, 0, 0, 0);
    }

    // C/D layout (verified m74/m101): col = lane&31, row = (g&3)+8*(g>>2)+4*(lane>>5)
    float* om0 = out + (size_t)(pair * 2) * (ND * ND);
    float* om1 = om0 + ND * ND;
    int col = lane & 31;
    int rb = (lane >> 5) * 4;
    #pragma unroll
    for (int g = 0; g < 16; ++g) {
        int row = (g & 3) + 8 * (g >> 2) + rb;
        om0[row * ND + col] = acc0[g];
        om1[row * ND + col] = acc1[g];
    }
}

extern "C" void kernel_launch(void* const* d_in, const int* in_sizes, int n_in,
                              void* d_out, int out_size, void* d_ws, size_t ws_size,
                              hipStream_t stream) {
    const float* X = (const float*)d_in[0];
    const float* s = (const float*)d_in[1];
    float* out = (float*)d_out;
    float* ws = (float*)d_ws;

    hipMemsetAsync(ws, 0, 1057 * sizeof(float), stream);
    hipLaunchKernelGGL(k1_stats, dim3(2048), dim3(256), 0, stream, X, ws);
    hipLaunchKernelGGL(k2_final, dim3(1), dim3(256), 0, stream, s, ws);
    hipLaunchKernelGGL(k3_out, dim3(4096), dim3(256), 0, stream, X, ws + 1088, out);
}

// Round 5
// 413.643 us; speedup vs baseline: 1.3367x; 1.2468x over previous
//
#include <hip/hip_runtime.h>
#include <cmath>

#define NM 32768   // 512 * 64 matrices
#define ND 32      // matrix side
#define NSLICE 16  // global-atomic accumulator slices (de-contention)
#define SLICE_STRIDE 1088
#define FMBASE (NSLICE * SLICE_STRIDE)   // 17408: fm block base

typedef __attribute__((ext_vector_type(8))) short short8;     // 8 bf16 (4 VGPRs)
typedef __attribute__((ext_vector_type(16))) float f32x16;    // MFMA accumulator

// Broadcast from lane L within each 32-lane group (ds_swizzle BitMode: and=0, or=L, xor=0)
template<int L>
__device__ __forceinline__ float bcast32(float x) {
    return __int_as_float(__builtin_amdgcn_ds_swizzle(__float_as_int(x), (L << 5)));
}

// ---------- Cholesky (right-looking, rank-1 updates). Lane r holds row r in a[0..31].
template<int J, int L>
__device__ __forceinline__ void rank1_upd(float (&a)[ND], float lrj) {
    if constexpr (L < ND) {
        float blj = bcast32<L>(lrj);          // L[l][J] from lane l
        a[L] = fmaf(-lrj, blj, a[L]);
        rank1_upd<J, L + 1>(a, lrj);
    }
}

template<int J>
__device__ __forceinline__ void chol_steps(float (&a)[ND], int r) {
    if constexpr (J < ND) {
        float ajj = bcast32<J>(a[J]);         // updated A[J][J] from lane J
        float d = sqrtf(ajj);
        float rinv = 1.0f / d;
        float lrj = (r == J) ? d : a[J] * rinv;  // final L[r][J] (garbage for r<J)
        a[J] = lrj;
        rank1_upd<J, J + 1>(a, lrj);
        chol_steps<J + 1>(a, r);
    }
}

union frag_u { short8 v; int i[4]; };

// Build complete MFMA fragments for both half-wave-resident matrices via
// __shfl_xor(.,32) cross-half exchange (verified R4).
__device__ __forceinline__ void build_frags(const frag_u& mine_lo, const frag_u& mine_hi,
                                            bool hi_half, frag_u& f0, frag_u& f1) {
    #pragma unroll
    for (int w = 0; w < 4; ++w) {
        int olo = __shfl_xor(mine_lo.i[w], 32);
        int ohi = __shfl_xor(mine_hi.i[w], 32);
        f0.i[w] = hi_half ? ohi : mine_lo.i[w];
        f1.i[w] = hi_half ? mine_hi.i[w] : olo;
    }
}

// ws layout (floats):
//   slice s in [0,16): [s*1088 .. s*1088+1056] partial sums
//       (0..1023: strictly-lower L sums TRANSPOSED slot j*32+r; 1024..1055: log-diag; 1056: S2)
//   [17408 .. 18431] : fmT = factor * sl_mean (transposed); [18432..18463]: fmd; [18464]: factor
// L itself is staged in d_out (k1 writes, k3 reads+overwrites).

__global__ __launch_bounds__(256) void k1_stats(const float* __restrict__ X,
                                                float* __restrict__ gacc,
                                                float* __restrict__ Lbuf) {
    __shared__ float lacc[1057];
    int tid = threadIdx.x;
    for (int i = tid; i < 1057; i += 256) lacc[i] = 0.0f;
    __syncthreads();

    int lane = tid & 63;
    int r = lane & 31;
    int wave = tid >> 6;

    for (int pass = 0; pass < 2; ++pass) {
        int mp = (blockIdx.x * 2 + pass) * 4 + wave;   // matrix-pair id
        int mat = mp * 2 + (lane >> 5);
        const float* xm = X + (size_t)mat * (ND * ND);

        float a[ND];
        #pragma unroll
        for (int j = 0; j < ND; ++j) a[j] = xm[j * ND + r];  // row r via symmetry (coalesced)

        chol_steps<0>(a, r);

        // stage L for k3 (transposed per-matrix layout, coalesced; upper slots
        // hold finite garbage, masked in k3)
        float* lm = Lbuf + (size_t)mat * (ND * ND);
        #pragma unroll
        for (int j = 0; j < ND; ++j) lm[j * ND + r] = a[j];

        float diag = a[0];
        #pragma unroll
        for (int j = 1; j < ND; ++j) diag = (r == j) ? a[j] : diag;
        float logd = logf(diag);

        float sq = logd * logd;
        #pragma unroll
        for (int j = 0; j < ND; ++j) if (j < r) sq = fmaf(a[j], a[j], sq);
        #pragma unroll
        for (int k = 1; k < 64; k <<= 1) sq += __shfl_xor(sq, k);
        if (lane == 0) atomicAdd(&lacc[1056], sq);

        #pragma unroll
        for (int j = 0; j < ND; ++j) if (j < r) atomicAdd(&lacc[j * ND + r], a[j]);
        atomicAdd(&lacc[1024 + r], logd);
    }

    __syncthreads();
    float* g = gacc + (size_t)(blockIdx.x & (NSLICE - 1)) * SLICE_STRIDE;
    for (int i = tid; i < 1057; i += 256) atomicAdd(&g[i], lacc[i]);
}

__global__ __launch_bounds__(256) void k2_final(const float* __restrict__ sscal,
                                                float* __restrict__ ws) {
    __shared__ float red[256];
    __shared__ float s2sh;
    __shared__ float sfactor;
    int tid = threadIdx.x;
    const float invM = 1.0f / (float)NM;

    float msq = 0.0f;
    for (int k = tid; k < 1057; k += 256) {
        float s = 0.0f;
        #pragma unroll
        for (int sl = 0; sl < NSLICE; ++sl) s += ws[sl * SLICE_STRIDE + k];
        if (k < 1056) {
            float m = s * invM;
            ws[FMBASE + k] = m;            // stash mean; scaled by factor below
            msq = fmaf(m, m, msq);
        } else {
            s2sh = s;
        }
    }
    red[tid] = msq;
    __syncthreads();
    for (int s = 128; s > 0; s >>= 1) {
        if (tid < s) red[tid] += red[tid + s];
        __syncthreads();
    }
    if (tid == 0) {
        float var = s2sh * invM - red[0];
        float f = sscal[0] / sqrtf(var);
        sfactor = f;
        ws[FMBASE + 1056] = f;
    }
    __syncthreads();
    float f = sfactor;
    for (int k = tid; k < 1056; k += 256) ws[FMBASE + k] *= f;
}

__global__ __launch_bounds__(256) void k3_out(const float* __restrict__ wsf,
                                              float* __restrict__ out) {
    int tid = threadIdx.x;
    int lane = tid & 63;
    int r = lane & 31;
    int wave = tid >> 6;
    int pair = blockIdx.x * 4 + wave;
    int mat = pair * 2 + (lane >> 5);
    bool hi_half = (lane >> 5) != 0;

    // load staged L (written by k1); this wave only reads its own pair's region
    const float* lm = out + (size_t)mat * (ND * ND);
    float a[ND];
    #pragma unroll
    for (int j = 0; j < ND; ++j) a[j] = lm[j * ND + r];

    float factor = wsf[1056];

    float diag = a[0];
    #pragma unroll
    for (int j = 1; j < ND; ++j) diag = (r == j) ? a[j] : diag;
    float dval = expf(fmaf(factor, logf(diag), -wsf[1024 + r]));

    // L_out row r: strict lower = factor*L - factor*mean; diag = dval; upper = 0
    #pragma unroll
    for (int j = 0; j < ND; ++j) {
        float b = fmaf(factor, a[j], -wsf[j * ND + r]);
        a[j] = (j < r) ? b : ((j == r) ? dval : 0.0f);
    }

    // ---- out = L_out * L_out^T via bf16 hi/lo MFMA (verified R4; err ~8e-3 incl. k-perm invariance)
    f32x16 acc0, acc1;
    #pragma unroll
    for (int g = 0; g < 16; ++g) { acc0[g] = 0.0f; acc1[g] = 0.0f; }

    #pragma unroll
    for (int kb = 0; kb < 32; kb += 16) {
        frag_u mlo_h, mhi_h, mlo_l, mhi_l;
        #pragma unroll
        for (int i = 0; i < 8; ++i) {
            float v0 = a[kb + i], v1 = a[kb + 8 + i];
            __bf16 hb0 = (__bf16)v0, hb1 = (__bf16)v1;
            mlo_h.v[i] = __builtin_bit_cast(short, hb0);
            mhi_h.v[i] = __builtin_bit_cast(short, hb1);
            mlo_l.v[i] = __builtin_bit_cast(short, (__bf16)(v0 - (float)hb0));
            mhi_l.v[i] = __builtin_bit_cast(short, (__bf16)(v1 - (float)hb1));
        }
        frag_u h0, h1, l0, l1;
        build_frags(mlo_h, mhi_h, hi_half, h0, h1);
        build_frags(mlo_l, mhi_l, hi_half, l0, l1);
        acc0 = __builtin_amdgcn_mfma_f32_32x32x16_bf16(h0.v, h0.v, acc0, 0, 0, 0);
        acc1 = __builtin_amdgcn_mfma_f32_32x32x16_bf16(h1.v, h1.v, acc1, 0, 0, 0);
        acc0 = __builtin_amdgcn_mfma_f32_32x32x16_bf16(h0.v, l0.v, acc0, 0, 0, 0);
        acc1 = __builtin_amdgcn_mfma_f32_32x32x16_bf16(h1.v, l1.v, acc1, 0, 0, 0);
        acc0 = __builtin_amdgcn_mfma_f32_32x32x16_bf16(l0.v, h0.v, acc0, 0, 0, 0);
        acc1 = __builtin_amdgcn_mfma_f32_32x32x16_bf16(l1.v, h1.v, acc1, 0, 0, 0);
    }

    // C/D layout (verified m74/m101): col = lane&31, row = (g&3)+8*(g>>2)+4*(lane>>5)
    float* om0 = out + (size_t)(pair * 2) * (ND * ND);
    float* om1 = om0 + ND * ND;
    int col = lane & 31;
    int rb = (lane >> 5) * 4;
    #pragma unroll
    for (int g = 0; g < 16; ++g) {
        int row = (g & 3) + 8 * (g >> 2) + rb;
        om0[row * ND + col] = acc0[g];
        om1[row * ND + col] = acc1[g];
    }
}

extern "C" void kernel_launch(void* const* d_in, const int* in_sizes, int n_in,
                              void* d_out, int out_size, void* d_ws, size_t ws_size,
                              hipStream_t stream) {
    const float* X = (const float*)d_in[0];
    const float* s = (const float*)d_in[1];
    float* out = (float*)d_out;
    float* ws = (float*)d_ws;

    hipMemsetAsync(ws, 0, NSLICE * SLICE_STRIDE * sizeof(float), stream);
    hipLaunchKernelGGL(k1_stats, dim3(2048), dim3(256), 0, stream, X, ws, out);
    hipLaunchKernelGGL(k2_final, dim3(1), dim3(256), 0, stream, s, ws);
    hipLaunchKernelGGL(k3_out, dim3(4096), dim3(256), 0, stream, ws + FMBASE, out);
}

// Round 6
// 347.397 us; speedup vs baseline: 1.5916x; 1.1907x over previous
//
#include <hip/hip_runtime.h>
#include <cmath>

#define NM 32768   // 512 * 64 matrices
#define ND 32      // matrix side
#define NSLICE 16  // global-atomic accumulator slices (de-contention)
#define SLICE_STRIDE 1088
#define FMBASE (NSLICE * SLICE_STRIDE)   // 17408: fm block base

typedef __attribute__((ext_vector_type(8))) short short8;     // 8 bf16 (4 VGPRs)
typedef __attribute__((ext_vector_type(16))) float f32x16;    // MFMA accumulator

// Broadcast from lane L within each 32-lane group (ds_swizzle BitMode: and=0, or=L, xor=0)
template<int L>
__device__ __forceinline__ float bcast32(float x) {
    return __int_as_float(__builtin_amdgcn_ds_swizzle(__float_as_int(x), (L << 5)));
}

// ---------- Cholesky (right-looking, rank-1 updates). Lane r holds row r in a[0..31].
// v_rsq_f32 replaces sqrt+div on the critical path (SPD => ajj > 0).
template<int J, int L>
__device__ __forceinline__ void rank1_upd(float (&a)[ND], float lrj) {
    if constexpr (L < ND) {
        float blj = bcast32<L>(lrj);          // L[l][J] from lane l
        a[L] = fmaf(-lrj, blj, a[L]);
        rank1_upd<J, L + 1>(a, lrj);
    }
}

template<int J>
__device__ __forceinline__ void chol_steps(float (&a)[ND], int r) {
    if constexpr (J < ND) {
        float ajj = bcast32<J>(a[J]);         // updated A[J][J] from lane J
        float rs = __builtin_amdgcn_rsqf(ajj);
        float lrj = ((r == J) ? ajj : a[J]) * rs;  // lane J: sqrt(ajj); others: a[J]/sqrt(ajj)
        a[J] = lrj;
        rank1_upd<J, J + 1>(a, lrj);
        chol_steps<J + 1>(a, r);
    }
}

union frag_u { short8 v; int i[4]; };

// Cross-half fragment exchange via __shfl_xor(.,32) (verified R4/R5).
__device__ __forceinline__ void build_frags(const frag_u& mine_lo, const frag_u& mine_hi,
                                            bool hi_half, frag_u& f0, frag_u& f1) {
    #pragma unroll
    for (int w = 0; w < 4; ++w) {
        int olo = __shfl_xor(mine_lo.i[w], 32);
        int ohi = __shfl_xor(mine_hi.i[w], 32);
        f0.i[w] = hi_half ? ohi : mine_lo.i[w];
        f1.i[w] = hi_half ? mine_hi.i[w] : olo;
    }
}

// ws layout (floats):
//   slice s in [0,16): [s*1088 .. s*1088+1056] partial sums
//   [17408 .. 18431]: fmT = factor*sl_mean (transposed j*32+r); [18432..18463]: f*logd_mean; [18464]: factor
// L staged in d_out (k1 writes, k3 reads+overwrites), transposed per-matrix: lm[j*32+r] = L[r][j].

__global__ __launch_bounds__(256, 4) void k1_stats(const float* __restrict__ X,
                                                   float* __restrict__ gacc,
                                                   float* __restrict__ Lbuf) {
    __shared__ float lacc[1057];
    int tid = threadIdx.x;
    for (int i = tid; i < 1057; i += 256) lacc[i] = 0.0f;
    __syncthreads();

    int lane = tid & 63;
    int r = lane & 31;
    int wave = tid >> 6;

    for (int pass = 0; pass < 2; ++pass) {
        int mp = (blockIdx.x * 2 + pass) * 4 + wave;   // matrix-pair id
        int mat = mp * 2 + (lane >> 5);
        const float* xm = X + (size_t)mat * (ND * ND);

        float a[ND];
        #pragma unroll
        for (int j = 0; j < ND; ++j) a[j] = xm[j * ND + r];  // row r via symmetry (coalesced)

        chol_steps<0>(a, r);

        // stage L for k3 (upper slots garbage, masked in k3)
        float* lm = Lbuf + (size_t)mat * (ND * ND);
        #pragma unroll
        for (int j = 0; j < ND; ++j) lm[j * ND + r] = a[j];

        float diag = a[0];
        #pragma unroll
        for (int j = 1; j < ND; ++j) diag = (r == j) ? a[j] : diag;
        float logd = logf(diag);

        float sq = logd * logd;
        #pragma unroll
        for (int j = 0; j < ND; ++j) if (j < r) sq = fmaf(a[j], a[j], sq);
        #pragma unroll
        for (int k = 1; k < 64; k <<= 1) sq += __shfl_xor(sq, k);
        if (lane == 0) atomicAdd(&lacc[1056], sq);

        #pragma unroll
        for (int j = 0; j < ND; ++j) if (j < r) atomicAdd(&lacc[j * ND + r], a[j]);
        atomicAdd(&lacc[1024 + r], logd);
    }

    __syncthreads();
    float* g = gacc + (size_t)(blockIdx.x & (NSLICE - 1)) * SLICE_STRIDE;
    for (int i = tid; i < 1057; i += 256) atomicAdd(&g[i], lacc[i]);
}

__global__ __launch_bounds__(256) void k2_final(const float* __restrict__ sscal,
                                                float* __restrict__ ws) {
    __shared__ float red[256];
    __shared__ float s2sh;
    __shared__ float sfactor;
    int tid = threadIdx.x;
    const float invM = 1.0f / (float)NM;

    float msq = 0.0f;
    for (int k = tid; k < 1057; k += 256) {
        float s = 0.0f;
        #pragma unroll
        for (int sl = 0; sl < NSLICE; ++sl) s += ws[sl * SLICE_STRIDE + k];
        if (k < 1056) {
            float m = s * invM;
            ws[FMBASE + k] = m;            // stash mean; scaled by factor below
            msq = fmaf(m, m, msq);
        } else {
            s2sh = s;
        }
    }
    red[tid] = msq;
    __syncthreads();
    for (int s = 128; s > 0; s >>= 1) {
        if (tid < s) red[tid] += red[tid + s];
        __syncthreads();
    }
    if (tid == 0) {
        float var = s2sh * invM - red[0];
        float f = sscal[0] / sqrtf(var);
        sfactor = f;
        ws[FMBASE + 1056] = f;
    }
    __syncthreads();
    float f = sfactor;
    for (int k = tid; k < 1056; k += 256) ws[FMBASE + k] *= f;
}

__global__ __launch_bounds__(256, 4) void k3_out(const float* __restrict__ wsf,
                                                 float* __restrict__ out) {
    int tid = threadIdx.x;
    int lane = tid & 63;
    int r = lane & 31;
    int wave = tid >> 6;
    int pair = blockIdx.x * 4 + wave;
    int mat = pair * 2 + (lane >> 5);
    bool hi_half = (lane >> 5) != 0;

    const float* lm = out + (size_t)mat * (ND * ND);
    float a[ND];
    #pragma unroll
    for (int j = 0; j < ND; ++j) a[j] = lm[j * ND + r];
    float diag = lm[r * ND + r];          // extra load, hits lines fetched above

    float factor = wsf[1056];
    float dval = expf(fmaf(factor, logf(diag), -wsf[1024 + r]));

    // Transform fused into bf16 hi/lo pack (keeps live fp32 window small):
    // elem j: j<r -> factor*L - f*mean; j==r -> dval; j>r -> 0.
    f32x16 acc0, acc1;
    #pragma unroll
    for (int g = 0; g < 16; ++g) { acc0[g] = 0.0f; acc1[g] = 0.0f; }

    #pragma unroll
    for (int kb = 0; kb < 32; kb += 16) {
        frag_u mlo_h, mhi_h, mlo_l, mhi_l;
        #pragma unroll
        for (int i = 0; i < 8; ++i) {
            int j0 = kb + i, j1 = kb + 8 + i;
            float t0 = fmaf(factor, a[j0], -wsf[j0 * ND + r]);
            float v0 = (j0 < r) ? t0 : ((j0 == r) ? dval : 0.0f);
            float t1 = fmaf(factor, a[j1], -wsf[j1 * ND + r]);
            float v1 = (j1 < r) ? t1 : ((j1 == r) ? dval : 0.0f);
            __bf16 hb0 = (__bf16)v0, hb1 = (__bf16)v1;
            mlo_h.v[i] = __builtin_bit_cast(short, hb0);
            mhi_h.v[i] = __builtin_bit_cast(short, hb1);
            mlo_l.v[i] = __builtin_bit_cast(short, (__bf16)(v0 - (float)hb0));
            mhi_l.v[i] = __builtin_bit_cast(short, (__bf16)(v1 - (float)hb1));
        }
        frag_u h0, h1, l0, l1;
        build_frags(mlo_h, mhi_h, hi_half, h0, h1);
        build_frags(mlo_l, mhi_l, hi_half, l0, l1);
        acc0 = __builtin_amdgcn_mfma_f32_32x32x16_bf16(h0.v, h0.v, acc0, 0, 0, 0);
        acc1 = __builtin_amdgcn_mfma_f32_32x32x16_bf16(h1.v, h1.v, acc1, 0, 0, 0);
        acc0 = __builtin_amdgcn_mfma_f32_32x32x16_bf16(h0.v, l0.v, acc0, 0, 0, 0);
        acc1 = __builtin_amdgcn_mfma_f32_32x32x16_bf16(h1.v, l1.v, acc1, 0, 0, 0);
        acc0 = __builtin_amdgcn_mfma_f32_32x32x16_bf16(l0.v, h0.v, acc0, 0, 0, 0);
        acc1 = __builtin_amdgcn_mfma_f32_32x32x16_bf16(l1.v, h1.v, acc1, 0, 0, 0);
    }

    // C/D layout (verified): col = lane&31, row = (g&3)+8*(g>>2)+4*(lane>>5)
    float* om0 = out + (size_t)(pair * 2) * (ND * ND);
    float* om1 = om0 + ND * ND;
    int col = lane & 31;
    int rb = (lane >> 5) * 4;
    #pragma unroll
    for (int g = 0; g < 16; ++g) {
        int row = (g & 3) + 8 * (g >> 2) + rb;
        om0[row * ND + col] = acc0[g];
        om1[row * ND + col] = acc1[g];
    }
}

extern "C" void kernel_launch(void* const* d_in, const int* in_sizes, int n_in,
                              void* d_out, int out_size, void* d_ws, size_t ws_size,
                              hipStream_t stream) {
    const float* X = (const float*)d_in[0];
    const float* s = (const float*)d_in[1];
    float* out = (float*)d_out;
    float* ws = (float*)d_ws;

    hipMemsetAsync(ws, 0, NSLICE * SLICE_STRIDE * sizeof(float), stream);
    hipLaunchKernelGGL(k1_stats, dim3(2048), dim3(256), 0, stream, X, ws, out);
    hipLaunchKernelGGL(k2_final, dim3(1), dim3(256), 0, stream, s, ws);
    hipLaunchKernelGGL(k3_out, dim3(4096), dim3(256), 0, stream, ws + FMBASE, out);
}